// Round 6
// baseline (176.188 us; speedup 1.0000x reference)
//
#include <hip/hip_runtime.h>
#include <hip/hip_bf16.h>
#include <math.h>

#define N_NODES 50000
#define N_EDGES 800000
#define E2 (N_EDGES + N_NODES)
#define D 128

#define NB_LN 12500
#define NB_W 128

#define BSHIFT 10
#define NBUCK 49  // ceil(50000 / 1024)
#define SCHUNK 4096
#define NB_SC ((E2 + SCHUNK - 1) / SCHUNK)

typedef short short8 __attribute__((ext_vector_type(8)));
typedef float f32x4 __attribute__((ext_vector_type(4)));
typedef float f32x2 __attribute__((ext_vector_type(2)));

__device__ __forceinline__ float waveReduceSum(float v) {
#pragma unroll
  for (int off = 32; off >= 1; off >>= 1) v += __shfl_xor(v, off);
  return v;
}

__device__ __forceinline__ float bf16hi(unsigned int r) {
  return __uint_as_float(r & 0xffff0000u);
}
__device__ __forceinline__ float bf16lo(unsigned int r) {
  return __uint_as_float(r << 16);
}

// Fused: LayerNorm->ReLU->hb + hnorm | W transpose+cvt | bucket count.
__global__ void __launch_bounds__(256) k_pre(
    const float* __restrict__ x, const float* __restrict__ gamma,
    const float* __restrict__ beta, const float* __restrict__ Wl,
    const float* __restrict__ Wr, const int* __restrict__ ei,
    __hip_bfloat16* __restrict__ hb, float* __restrict__ hnorm,
    __hip_bfloat16* __restrict__ Wt, int* __restrict__ bcnt) {
  const int b = blockIdx.x;
  if (b < NB_LN) {
    int wid = threadIdx.x >> 6;
    int lane = threadIdx.x & 63;
    int i = b * 4 + wid;
    const float2 xv = *(const float2*)&x[(size_t)i * D + lane * 2];
    float s = waveReduceSum(xv.x + xv.y);
    float mean = s * (1.0f / D);
    float d0 = xv.x - mean, d1 = xv.y - mean;
    float vs = waveReduceSum(d0 * d0 + d1 * d1);
    float rstd = rsqrtf(vs * (1.0f / D) + 1e-5f);
    const float2 g = *(const float2*)&gamma[lane * 2];
    const float2 bb = *(const float2*)&beta[lane * 2];
    float h0 = fmaxf(d0 * rstd * g.x + bb.x, 0.0f);
    float h1 = fmaxf(d1 * rstd * g.y + bb.y, 0.0f);
    __hip_bfloat162 hv;
    hv.x = __float2bfloat16(h0);
    hv.y = __float2bfloat16(h1);
    *(__hip_bfloat162*)&hb[(size_t)i * D + lane * 2] = hv;
    float ns = waveReduceSum(h0 * h0 + h1 * h1);
    if (lane == 0) hnorm[i] = sqrtf(ns);
  } else if (b < NB_LN + NB_W) {
    int local = b - NB_LN;
    int n = local * 2 + (threadIdx.x >> 7);
    int k = threadIdx.x & 127;
    float v = (n < D) ? Wl[(size_t)k * D + n] : Wr[(size_t)k * D + (n - D)];
    Wt[n * D + k] = __float2bfloat16(v);
  } else {
    __shared__ int c[64];
    const int t = threadIdx.x;
    if (t < 64) c[t] = 0;
    __syncthreads();
    const int s0 = (b - NB_LN - NB_W) * SCHUNK;
#pragma unroll
    for (int k = 0; k < 16; ++k) {
      int e = s0 + t + k * 256;
      if (e < E2) {
        int dst = (e < N_EDGES) ? ei[N_EDGES + e] : (e - N_EDGES);
        atomicAdd(&c[dst >> BSHIFT], 1);
      }
    }
    __syncthreads();
    if (t < 64 && c[t]) atomicAdd(&bcnt[t], c[t]);
  }
}

// LDS-free bf16 MFMA GEMM. Block = 128 rows x 128 cols (nhalf picks Wl/Wr),
// 4 waves each 64x64. Fragments loaded straight from global (hb/Wt are
// L2/L3-resident; each fragment load consumes full 64B lines).
__global__ void __launch_bounds__(256) k_gemm2(
    const __hip_bfloat16* __restrict__ hb, const __hip_bfloat16* __restrict__ Wt,
    const float* __restrict__ bL, const float* __restrict__ bR,
    __hip_bfloat16* __restrict__ xlb, __hip_bfloat16* __restrict__ xrb) {
  const int t = threadIdx.x;
  const int w = t >> 6, lane = t & 63;
  const int row0 = blockIdx.x * 128;
  const int nhalf = blockIdx.y;
  const int wm = (w >> 1) * 64, wn = (w & 1) * 64;
  const int lr = lane & 15, lq = lane >> 4;
  const unsigned short* hu = (const unsigned short*)hb;
  const unsigned short* wu = (const unsigned short*)Wt;
  int arow[4], brow[4];
#pragma unroll
  for (int mi = 0; mi < 4; ++mi)
    arow[mi] = min(row0 + wm + mi * 16 + lr, N_NODES - 1);
#pragma unroll
  for (int ni = 0; ni < 4; ++ni) brow[ni] = nhalf * 128 + wn + ni * 16 + lr;
  f32x4 acc[4][4] = {};
#pragma unroll
  for (int kb = 0; kb < 4; ++kb) {
    const int ko = kb * 32 + lq * 8;
    short8 af[4], bfr[4];
#pragma unroll
    for (int mi = 0; mi < 4; ++mi)
      af[mi] = *(const short8*)&hu[(size_t)arow[mi] * D + ko];
#pragma unroll
    for (int ni = 0; ni < 4; ++ni)
      bfr[ni] = *(const short8*)&wu[(size_t)brow[ni] * D + ko];
#pragma unroll
    for (int mi = 0; mi < 4; ++mi)
#pragma unroll
      for (int ni = 0; ni < 4; ++ni)
        acc[mi][ni] =
            __builtin_amdgcn_mfma_f32_16x16x32_bf16(af[mi], bfr[ni], acc[mi][ni], 0, 0, 0);
  }
  const float* bb = (nhalf == 0) ? bL : bR;
  __hip_bfloat16* dst = (nhalf == 0) ? xlb : xrb;
#pragma unroll
  for (int ni = 0; ni < 4; ++ni) {
    const int col = wn + ni * 16 + lr;
    const float bv = bb[col];
#pragma unroll
    for (int mi = 0; mi < 4; ++mi) {
#pragma unroll
      for (int r = 0; r < 4; ++r) {
        int row = row0 + wm + mi * 16 + lq * 4 + r;
        if (row < N_NODES)
          dst[(size_t)row * D + col] = __float2bfloat16(acc[mi][ni][r] + bv);
      }
    }
  }
}

// Exclusive scan of bucket counts (single wave) + csr tail padding.
__global__ void k_bscan(const int* __restrict__ bcnt, int* __restrict__ boff,
                        int* __restrict__ bcur, int* __restrict__ rowptr,
                        int* __restrict__ csr) {
  const int t = threadIdx.x;  // 64 threads
  int v = (t < NBUCK) ? bcnt[t] : 0;
  int incl = v;
#pragma unroll
  for (int off = 1; off < 64; off <<= 1) {
    int u = __shfl_up(incl, off);
    if (t >= off) incl += u;
  }
  int excl = incl - v;
  if (t < NBUCK) {
    boff[t] = excl;
    bcur[t] = excl;
  }
  if (t == NBUCK - 1) {
    boff[NBUCK] = incl;  // == E2
    rowptr[N_NODES] = incl;
  }
  if (t < 16) csr[E2 + t] = 0;  // sentinel pad: k_node overreads up to +11
}

// Scatter (src,dst) pairs into bucket-grouped array. Per-block two-phase.
__global__ void __launch_bounds__(256) k_bscatter(const int* __restrict__ ei,
                                                  int* __restrict__ bcur,
                                                  int2* __restrict__ bucketed) {
  __shared__ int c[64], base[64];
  const int t = threadIdx.x;
  if (t < 64) c[t] = 0;
  __syncthreads();
  const int s0 = blockIdx.x * SCHUNK;
#pragma unroll
  for (int k = 0; k < 16; ++k) {
    int e = s0 + t + k * 256;
    if (e < E2) {
      int dst = (e < N_EDGES) ? ei[N_EDGES + e] : (e - N_EDGES);
      atomicAdd(&c[dst >> BSHIFT], 1);
    }
  }
  __syncthreads();
  if (t < 64) {
    base[t] = c[t] ? atomicAdd(&bcur[t], c[t]) : 0;
    c[t] = 0;
  }
  __syncthreads();
#pragma unroll
  for (int k = 0; k < 16; ++k) {
    int e = s0 + t + k * 256;
    if (e < E2) {
      int src, dst;
      if (e < N_EDGES) {
        src = ei[e];
        dst = ei[N_EDGES + e];
      } else {
        src = dst = e - N_EDGES;
      }
      int b = dst >> BSHIFT;
      int pos = base[b] + atomicAdd(&c[b], 1);
      bucketed[pos] = make_int2(src, dst);
    }
  }
}

// One block per bucket: degree count + scan in LDS -> rowptr, then scatter
// csr within the bucket's contiguous (L2-local) window.
__global__ void __launch_bounds__(256) k_csr(const int2* __restrict__ bucketed,
                                             const int* __restrict__ boff,
                                             int* __restrict__ rowptr,
                                             int* __restrict__ csr) {
  __shared__ int cnt[1024], tsum[256], cursor[1024];
  const int b = blockIdx.x;
  const int base = b << BSHIFT;
  const int nnode = min(1024, N_NODES - base);
  const int t = threadIdx.x;
  const int e0 = boff[b], e1 = boff[b + 1];
  for (int n = t; n < 1024; n += 256) cnt[n] = 0;
  __syncthreads();
  for (int e = e0 + t; e < e1; e += 256) {
    int2 pr = bucketed[e];
    atomicAdd(&cnt[pr.y - base], 1);
  }
  __syncthreads();
  const int n0 = t * 4;
  const int c0 = cnt[n0], c1 = cnt[n0 + 1], c2 = cnt[n0 + 2], c3 = cnt[n0 + 3];
  const int s = c0 + c1 + c2 + c3;
  tsum[t] = s;
  __syncthreads();
  for (int off = 1; off < 256; off <<= 1) {
    int u = 0;
    if (t >= off) u = tsum[t - off];
    __syncthreads();
    if (t >= off) tsum[t] += u;
    __syncthreads();
  }
  const int ebase = e0 + tsum[t] - s;  // exclusive prefix
  const int r0 = ebase, r1 = r0 + c0, r2 = r1 + c1, r3 = r2 + c2;
  cursor[n0] = r0;
  cursor[n0 + 1] = r1;
  cursor[n0 + 2] = r2;
  cursor[n0 + 3] = r3;
  if (n0 < nnode) rowptr[base + n0] = r0;
  if (n0 + 1 < nnode) rowptr[base + n0 + 1] = r1;
  if (n0 + 2 < nnode) rowptr[base + n0 + 2] = r2;
  if (n0 + 3 < nnode) rowptr[base + n0 + 3] = r3;
  __syncthreads();
  for (int e = e0 + t; e < e1; e += 256) {
    int2 pr = bucketed[e];
    int pos = atomicAdd(&cursor[pr.y - base], 1);
    csr[pos] = pr.x;
  }
}

// Fused GATv2 edge phase. One wave per node; 4 edges per iteration
// (16 lanes/edge, 8 dims/lane as 4 f32x2 pairs -> v_pk_* math).
// Direct exp (scores O(+-3), softmax shift-invariant). csr overreads land in
// the next segment / sentinel pad and are masked via ok.
__global__ void __launch_bounds__(256) k_node(
    const float* __restrict__ x, const __hip_bfloat16* __restrict__ xlb,
    const __hip_bfloat16* __restrict__ xrb, const float* __restrict__ hnorm,
    const int* __restrict__ rowptr, const int* __restrict__ csr,
    const float* __restrict__ att, const float* __restrict__ bias,
    const float* __restrict__ scale, float* __restrict__ out) {
  const int wid = threadIdx.x >> 6;
  const int lane = threadIdx.x & 63;
  const int i = blockIdx.x * 4 + wid;
  if (i >= N_NODES) return;
  const int g = lane >> 4;  // edge subgroup 0..3
  const int q = lane & 15;  // dim quad: dims q*8 .. q*8+7 ; head = q>>2
  const unsigned short* xu = (const unsigned short*)xlb;

  f32x2 xr2[4], at2[4];
  {
    const uint4 rv = *(const uint4*)((const unsigned short*)xrb + (size_t)i * D + q * 8);
    const unsigned int rr[4] = {rv.x, rv.y, rv.z, rv.w};
    const float4 a0 = *(const float4*)&att[q * 8];
    const float4 a1 = *(const float4*)&att[q * 8 + 4];
#pragma unroll
    for (int z = 0; z < 4; ++z) {
      xr2[z].x = bf16lo(rr[z]);
      xr2[z].y = bf16hi(rr[z]);
    }
    at2[0] = (f32x2){a0.x, a0.y};
    at2[1] = (f32x2){a0.z, a0.w};
    at2[2] = (f32x2){a1.x, a1.y};
    at2[3] = (f32x2){a1.z, a1.w};
  }

  const int e0 = rowptr[i], e1 = rowptr[i + 1];
  f32x2 A2[4] = {};
  float S = 0.f;

  int jc = csr[e0 + g];
  uint4 rv = *(const uint4*)(xu + (size_t)jc * D + q * 8);
  int jn = csr[e0 + 4 + g];

  for (int e = e0; e < e1; e += 4) {
    const uint4 cur = rv;
    const int jnn = csr[e + 8 + g];
    rv = *(const uint4*)(xu + (size_t)jn * D + q * 8);
    jn = jnn;
    const bool ok = (e + g) < e1;

    const unsigned int rr[4] = {cur.x, cur.y, cur.z, cur.w};
    f32x2 v2[4];
    f32x2 sc2 = {};
#pragma unroll
    for (int z = 0; z < 4; ++z) {
      v2[z].x = bf16lo(rr[z]);
      v2[z].y = bf16hi(rr[z]);
      f32x2 f = v2[z] + xr2[z];
      f32x2 lf = __builtin_elementwise_max(f, f * 0.2f);
      sc2 = lf * at2[z] + sc2;
    }
    float sc = sc2.x + sc2.y;
    sc += __shfl_xor(sc, 1);
    sc += __shfl_xor(sc, 2);
    const float p = ok ? __expf(sc) : 0.f;
    S += p;
    const f32x2 p2 = {p, p};
#pragma unroll
    for (int z = 0; z < 4; ++z) A2[z] = v2[z] * p2 + A2[z];
  }

  // combine the 4 edge subgroups (lanes l, l+16, l+32, l+48 share dims)
#pragma unroll
  for (int off = 16; off <= 32; off <<= 1) {
#pragma unroll
    for (int z = 0; z < 4; ++z) {
      A2[z].x += __shfl_xor(A2[z].x, off);
      A2[z].y += __shfl_xor(A2[z].y, off);
    }
    S += __shfl_xor(S, off);
  }

  const float si = 1.0f / S;
  float o[8];
  float b8[8];
  *(float4*)&b8[0] = *(const float4*)&bias[q * 8];
  *(float4*)&b8[4] = *(const float4*)&bias[q * 8 + 4];
  float dot = 0.f;
#pragma unroll
  for (int z = 0; z < 4; ++z) {
    o[2 * z] = fmaf(A2[z].x, si, b8[2 * z]);
    o[2 * z + 1] = fmaf(A2[z].y, si, b8[2 * z + 1]);
    dot = fmaf(o[2 * z], o[2 * z], dot);
    dot = fmaf(o[2 * z + 1], o[2 * z + 1], dot);
  }
  const float nrm = sqrtf(waveReduceSum(dot) * 0.25f);  // dims replicated 4x
  const float gg = hnorm[i] * scale[0] / fmaxf(nrm, 1e-12f);

  if (lane < 16) {
    float x8[8];
    *(float4*)&x8[0] = *(const float4*)&x[(size_t)i * D + q * 8];
    *(float4*)&x8[4] = *(const float4*)&x[(size_t)i * D + q * 8 + 4];
    float r8[8];
#pragma unroll
    for (int z = 0; z < 8; ++z) r8[z] = fmaf(o[z], gg, x8[z]);
    *(float4*)&out[(size_t)i * D + q * 8] = *(float4*)&r8[0];
    *(float4*)&out[(size_t)i * D + q * 8 + 4] = *(float4*)&r8[4];
  }
}

extern "C" void kernel_launch(void* const* d_in, const int* in_sizes, int n_in,
                              void* d_out, int out_size, void* d_ws, size_t ws_size,
                              hipStream_t stream) {
  const float* x = (const float*)d_in[0];
  const int* ei = (const int*)d_in[1];
  const float* gamma = (const float*)d_in[2];
  const float* beta = (const float*)d_in[3];
  const float* Wl = (const float*)d_in[4];
  const float* bL = (const float*)d_in[5];
  const float* Wr = (const float*)d_in[6];
  const float* bR = (const float*)d_in[7];
  const float* att = (const float*)d_in[8];
  const float* bias = (const float*)d_in[9];
  const float* scale = (const float*)d_in[10];
  float* out = (float*)d_out;

  // workspace layout (~49 MB)
  int2* bucketed = (int2*)d_ws;             // E2 pairs
  int* csr = (int*)(bucketed + E2);         // E2 + 16 (sentinel pad)
  int* rowptr = csr + E2 + 16;              // N+1
  int* bcnt = rowptr + N_NODES + 1;         // 64
  int* boff = bcnt + 64;                    // NBUCK+1 (pad 64)
  int* bcur = boff + 64;                    // 64
  float* hnorm = (float*)(bcur + 64);       // N
  __hip_bfloat16* hb = (__hip_bfloat16*)(hnorm + N_NODES);
  __hip_bfloat16* xlb = hb + (size_t)N_NODES * D;
  __hip_bfloat16* xrb = xlb + (size_t)N_NODES * D;
  __hip_bfloat16* Wt = xrb + (size_t)N_NODES * D;  // 256*128

  hipMemsetAsync(bcnt, 0, 64 * sizeof(int), stream);
  k_pre<<<NB_LN + NB_W + NB_SC, 256, 0, stream>>>(x, gamma, beta, Wl, Wr, ei, hb,
                                                  hnorm, Wt, bcnt);
  k_bscan<<<1, 64, 0, stream>>>(bcnt, boff, bcur, rowptr, csr);
  k_bscatter<<<NB_SC, 256, 0, stream>>>(ei, bcur, bucketed);
  k_csr<<<NBUCK, 256, 0, stream>>>(bucketed, boff, rowptr, csr);
  k_gemm2<<<dim3((N_NODES + 127) / 128, 2), 256, 0, stream>>>(hb, Wt, bL, bR, xlb, xrb);
  k_node<<<(N_NODES + 3) / 4, 256, 0, stream>>>(x, xlb, xrb, hnorm, rowptr, csr, att,
                                                bias, scale, out);
}

// Round 7
// 163.398 us; speedup vs baseline: 1.0783x; 1.0783x over previous
//
#include <hip/hip_runtime.h>
#include <hip/hip_bf16.h>
#include <math.h>

#define N_NODES 50000
#define N_EDGES 800000
#define E2 (N_EDGES + N_NODES)
#define D 128

#define NB_LN 12500
#define NB_W 128

#define BSHIFT 10
#define NBUCK 49  // ceil(50000 / 1024)
#define SCHUNK 4096
#define NB_SC ((E2 + SCHUNK - 1) / SCHUNK)

typedef short short8 __attribute__((ext_vector_type(8)));
typedef float f32x4 __attribute__((ext_vector_type(4)));
typedef _Float16 h16x2 __attribute__((ext_vector_type(2)));
typedef _Float16 h16x8 __attribute__((ext_vector_type(8)));

__device__ __forceinline__ float waveReduceSum(float v) {
#pragma unroll
  for (int off = 32; off >= 1; off >>= 1) v += __shfl_xor(v, off);
  return v;
}

// Fused: LayerNorm->ReLU->hb + hnorm | W transpose+cvt | bucket count.
__global__ void __launch_bounds__(256) k_pre(
    const float* __restrict__ x, const float* __restrict__ gamma,
    const float* __restrict__ beta, const float* __restrict__ Wl,
    const float* __restrict__ Wr, const int* __restrict__ ei,
    __hip_bfloat16* __restrict__ hb, float* __restrict__ hnorm,
    __hip_bfloat16* __restrict__ Wt, int* __restrict__ bcnt) {
  const int b = blockIdx.x;
  if (b < NB_LN) {
    int wid = threadIdx.x >> 6;
    int lane = threadIdx.x & 63;
    int i = b * 4 + wid;
    const float2 xv = *(const float2*)&x[(size_t)i * D + lane * 2];
    float s = waveReduceSum(xv.x + xv.y);
    float mean = s * (1.0f / D);
    float d0 = xv.x - mean, d1 = xv.y - mean;
    float vs = waveReduceSum(d0 * d0 + d1 * d1);
    float rstd = rsqrtf(vs * (1.0f / D) + 1e-5f);
    const float2 g = *(const float2*)&gamma[lane * 2];
    const float2 bb = *(const float2*)&beta[lane * 2];
    float h0 = fmaxf(d0 * rstd * g.x + bb.x, 0.0f);
    float h1 = fmaxf(d1 * rstd * g.y + bb.y, 0.0f);
    __hip_bfloat162 hv;
    hv.x = __float2bfloat16(h0);
    hv.y = __float2bfloat16(h1);
    *(__hip_bfloat162*)&hb[(size_t)i * D + lane * 2] = hv;
    float ns = waveReduceSum(h0 * h0 + h1 * h1);
    if (lane == 0) hnorm[i] = sqrtf(ns);
  } else if (b < NB_LN + NB_W) {
    int local = b - NB_LN;
    int n = local * 2 + (threadIdx.x >> 7);
    int k = threadIdx.x & 127;
    float v = (n < D) ? Wl[(size_t)k * D + n] : Wr[(size_t)k * D + (n - D)];
    Wt[n * D + k] = __float2bfloat16(v);
  } else {
    __shared__ int c[64];
    const int t = threadIdx.x;
    if (t < 64) c[t] = 0;
    __syncthreads();
    const int s0 = (b - NB_LN - NB_W) * SCHUNK;
#pragma unroll
    for (int k = 0; k < 16; ++k) {
      int e = s0 + t + k * 256;
      if (e < E2) {
        int dst = (e < N_EDGES) ? ei[N_EDGES + e] : (e - N_EDGES);
        atomicAdd(&c[dst >> BSHIFT], 1);
      }
    }
    __syncthreads();
    if (t < 64 && c[t]) atomicAdd(&bcnt[t], c[t]);
  }
}

// bf16 MFMA GEMM: 128x128 tile, K=128 in LDS, 4 waves each 64x64.
// Output stored as f16 (feeds packed-f16 k_node math).
__global__ void __launch_bounds__(256) k_gemm2(
    const __hip_bfloat16* __restrict__ hb, const __hip_bfloat16* __restrict__ Wt,
    const float* __restrict__ bL, const float* __restrict__ bR,
    _Float16* __restrict__ xlh, _Float16* __restrict__ xrh) {
  __shared__ unsigned short As[128 * 128];
  __shared__ unsigned short Bs[128 * 128];
  const int t = threadIdx.x;
  const int row0 = blockIdx.x * 128;
  const int nhalf = blockIdx.y;
  const unsigned short* hu = (const unsigned short*)hb;
  const unsigned short* wu = (const unsigned short*)Wt;
#pragma unroll
  for (int it = 0; it < 8; ++it) {
    int idx = t + it * 256;
    int r = idx >> 4, g = idx & 15;
    int gs = g ^ (r & 15);
    short8 av = {};
    int grow = row0 + r;
    if (grow < N_NODES) av = *(const short8*)&hu[(size_t)grow * D + g * 8];
    *(short8*)&As[r * 128 + gs * 8] = av;
    short8 bv = *(const short8*)&wu[(size_t)(nhalf * 128 + r) * D + g * 8];
    *(short8*)&Bs[r * 128 + gs * 8] = bv;
  }
  __syncthreads();
  const int w = t >> 6, lane = t & 63;
  const int wm = (w >> 1) * 64, wn = (w & 1) * 64;
  const int lr = lane & 15, lq = lane >> 4;
  f32x4 acc[4][4] = {};
#pragma unroll
  for (int kb = 0; kb < 4; ++kb) {
    short8 af[4], bfr[4];
#pragma unroll
    for (int mi = 0; mi < 4; ++mi) {
      int r = wm + mi * 16 + lr;
      int g = (kb * 4 + lq) ^ (r & 15);
      af[mi] = *(const short8*)&As[r * 128 + g * 8];
    }
#pragma unroll
    for (int ni = 0; ni < 4; ++ni) {
      int r = wn + ni * 16 + lr;
      int g = (kb * 4 + lq) ^ (r & 15);
      bfr[ni] = *(const short8*)&Bs[r * 128 + g * 8];
    }
#pragma unroll
    for (int mi = 0; mi < 4; ++mi)
#pragma unroll
      for (int ni = 0; ni < 4; ++ni)
        acc[mi][ni] =
            __builtin_amdgcn_mfma_f32_16x16x32_bf16(af[mi], bfr[ni], acc[mi][ni], 0, 0, 0);
  }
  const float* bb = (nhalf == 0) ? bL : bR;
  _Float16* dst = (nhalf == 0) ? xlh : xrh;
#pragma unroll
  for (int mi = 0; mi < 4; ++mi) {
#pragma unroll
    for (int ni = 0; ni < 4; ++ni) {
#pragma unroll
      for (int r = 0; r < 4; ++r) {
        int row = row0 + wm + mi * 16 + lq * 4 + r;
        int col = wn + ni * 16 + lr;
        if (row < N_NODES)
          dst[(size_t)row * D + col] = (_Float16)(acc[mi][ni][r] + bb[col]);
      }
    }
  }
}

// Exclusive scan of bucket counts (single wave).
__global__ void k_bscan(const int* __restrict__ bcnt, int* __restrict__ boff,
                        int* __restrict__ bcur, int* __restrict__ rowptr) {
  const int t = threadIdx.x;  // 64 threads
  int v = (t < NBUCK) ? bcnt[t] : 0;
  int incl = v;
#pragma unroll
  for (int off = 1; off < 64; off <<= 1) {
    int u = __shfl_up(incl, off);
    if (t >= off) incl += u;
  }
  int excl = incl - v;
  if (t < NBUCK) {
    boff[t] = excl;
    bcur[t] = excl;
  }
  if (t == NBUCK - 1) {
    boff[NBUCK] = incl;  // == E2
    rowptr[N_NODES] = incl;
  }
}

// Scatter (src,dst) pairs into bucket-grouped array. Per-block two-phase.
__global__ void __launch_bounds__(256) k_bscatter(const int* __restrict__ ei,
                                                  int* __restrict__ bcur,
                                                  int2* __restrict__ bucketed) {
  __shared__ int c[64], base[64];
  const int t = threadIdx.x;
  if (t < 64) c[t] = 0;
  __syncthreads();
  const int s0 = blockIdx.x * SCHUNK;
#pragma unroll
  for (int k = 0; k < 16; ++k) {
    int e = s0 + t + k * 256;
    if (e < E2) {
      int dst = (e < N_EDGES) ? ei[N_EDGES + e] : (e - N_EDGES);
      atomicAdd(&c[dst >> BSHIFT], 1);
    }
  }
  __syncthreads();
  if (t < 64) {
    base[t] = c[t] ? atomicAdd(&bcur[t], c[t]) : 0;
    c[t] = 0;
  }
  __syncthreads();
#pragma unroll
  for (int k = 0; k < 16; ++k) {
    int e = s0 + t + k * 256;
    if (e < E2) {
      int src, dst;
      if (e < N_EDGES) {
        src = ei[e];
        dst = ei[N_EDGES + e];
      } else {
        src = dst = e - N_EDGES;
      }
      int b = dst >> BSHIFT;
      int pos = base[b] + atomicAdd(&c[b], 1);
      bucketed[pos] = make_int2(src, dst);
    }
  }
}

// One block per bucket: degree count + scan in LDS -> rowptr, then scatter
// csr within the bucket's contiguous (L2-local) window.
__global__ void __launch_bounds__(256) k_csr(const int2* __restrict__ bucketed,
                                             const int* __restrict__ boff,
                                             int* __restrict__ rowptr,
                                             int* __restrict__ csr) {
  __shared__ int cnt[1024], tsum[256], cursor[1024];
  const int b = blockIdx.x;
  const int base = b << BSHIFT;
  const int nnode = min(1024, N_NODES - base);
  const int t = threadIdx.x;
  const int e0 = boff[b], e1 = boff[b + 1];
  for (int n = t; n < 1024; n += 256) cnt[n] = 0;
  __syncthreads();
  for (int e = e0 + t; e < e1; e += 256) {
    int2 pr = bucketed[e];
    atomicAdd(&cnt[pr.y - base], 1);
  }
  __syncthreads();
  const int n0 = t * 4;
  const int c0 = cnt[n0], c1 = cnt[n0 + 1], c2 = cnt[n0 + 2], c3 = cnt[n0 + 3];
  const int s = c0 + c1 + c2 + c3;
  tsum[t] = s;
  __syncthreads();
  for (int off = 1; off < 256; off <<= 1) {
    int u = 0;
    if (t >= off) u = tsum[t - off];
    __syncthreads();
    if (t >= off) tsum[t] += u;
    __syncthreads();
  }
  const int ebase = e0 + tsum[t] - s;  // exclusive prefix
  const int r0 = ebase, r1 = r0 + c0, r2 = r1 + c1, r3 = r2 + c2;
  cursor[n0] = r0;
  cursor[n0 + 1] = r1;
  cursor[n0 + 2] = r2;
  cursor[n0 + 3] = r3;
  if (n0 < nnode) rowptr[base + n0] = r0;
  if (n0 + 1 < nnode) rowptr[base + n0 + 1] = r1;
  if (n0 + 2 < nnode) rowptr[base + n0 + 2] = r2;
  if (n0 + 3 < nnode) rowptr[base + n0 + 3] = r3;
  __syncthreads();
  for (int e = e0 + t; e < e1; e += 256) {
    int2 pr = bucketed[e];
    int pos = atomicAdd(&cursor[pr.y - base], 1);
    csr[pos] = pr.x;
  }
}

// Fused GATv2 edge phase. One wave per node; 4 edges per iteration
// (16 lanes/edge, 8 dims/lane). Packed f16 score math (v_pk_add/mul/max_f16 +
// v_dot2_f32_f16), f32 aggregation. Direct exp (scores O(+-3), softmax
// shift-invariant, fp32-safe).
__global__ void __launch_bounds__(256) k_node(
    const float* __restrict__ x, const _Float16* __restrict__ xlh,
    const _Float16* __restrict__ xrh, const float* __restrict__ hnorm,
    const int* __restrict__ rowptr, const int* __restrict__ csr,
    const float* __restrict__ att, const float* __restrict__ bias,
    const float* __restrict__ scale, float* __restrict__ out) {
  const int wid = threadIdx.x >> 6;
  const int lane = threadIdx.x & 63;
  const int i = blockIdx.x * 4 + wid;
  if (i >= N_NODES) return;
  const int g = lane >> 4;  // edge subgroup 0..3
  const int q = lane & 15;  // dim quad: dims q*8 .. q*8+7 ; head = q>>2

  // xr (this node's dims) and att as packed f16 pairs
  const h16x8 xrv = *(const h16x8*)(xrh + (size_t)i * D + q * 8);
  h16x2 xr2[4], at2[4];
  {
    const float4 a0 = *(const float4*)&att[q * 8];
    const float4 a1 = *(const float4*)&att[q * 8 + 4];
    at2[0] = (h16x2){(_Float16)a0.x, (_Float16)a0.y};
    at2[1] = (h16x2){(_Float16)a0.z, (_Float16)a0.w};
    at2[2] = (h16x2){(_Float16)a1.x, (_Float16)a1.y};
    at2[3] = (h16x2){(_Float16)a1.z, (_Float16)a1.w};
#pragma unroll
    for (int z = 0; z < 4; ++z) xr2[z] = (h16x2){xrv[2 * z], xrv[2 * z + 1]};
  }
  const h16x2 c02 = {(_Float16)0.2f, (_Float16)0.2f};

  const int e0 = rowptr[i], e1 = rowptr[i + 1];
  float A[8] = {};
  float S = 0.f;

  int jc = csr[min(e0 + g, e1 - 1)];
  h16x8 rv = *(const h16x8*)(xlh + (size_t)jc * D + q * 8);
  int jn = csr[min(e0 + 4 + g, e1 - 1)];

  for (int e = e0; e < e1; e += 4) {
    const h16x8 cur = rv;
    const int jnn = csr[min(e + 8 + g, e1 - 1)];
    rv = *(const h16x8*)(xlh + (size_t)jn * D + q * 8);
    jn = jnn;
    const bool ok = (e + g) < e1;

    float sc = 0.f;
#pragma unroll
    for (int z = 0; z < 4; ++z) {
      h16x2 v2 = {cur[2 * z], cur[2 * z + 1]};
      h16x2 f = v2 + xr2[z];
      h16x2 lf = __builtin_elementwise_max(f, f * c02);
      sc = __builtin_amdgcn_fdot2(lf, at2[z], sc, false);
    }
    sc += __shfl_xor(sc, 1);
    sc += __shfl_xor(sc, 2);
    const float p = ok ? __expf(sc) : 0.f;
    S += p;
#pragma unroll
    for (int z = 0; z < 8; ++z) A[z] = fmaf(p, (float)cur[z], A[z]);
  }

  // combine the 4 edge subgroups (lanes l, l+16, l+32, l+48 share dims)
#pragma unroll
  for (int off = 16; off <= 32; off <<= 1) {
#pragma unroll
    for (int z = 0; z < 8; ++z) A[z] += __shfl_xor(A[z], off);
    S += __shfl_xor(S, off);
  }

  const float si = 1.0f / S;
  float o[8];
  float b8[8];
  *(float4*)&b8[0] = *(const float4*)&bias[q * 8];
  *(float4*)&b8[4] = *(const float4*)&bias[q * 8 + 4];
  float dot = 0.f;
#pragma unroll
  for (int z = 0; z < 8; ++z) {
    o[z] = fmaf(A[z], si, b8[z]);
    dot = fmaf(o[z], o[z], dot);
  }
  const float nrm = sqrtf(waveReduceSum(dot) * 0.25f);  // dims replicated 4x
  const float gg = hnorm[i] * scale[0] / fmaxf(nrm, 1e-12f);

  if (lane < 16) {
    float x8[8];
    *(float4*)&x8[0] = *(const float4*)&x[(size_t)i * D + q * 8];
    *(float4*)&x8[4] = *(const float4*)&x[(size_t)i * D + q * 8 + 4];
    float r8[8];
#pragma unroll
    for (int z = 0; z < 8; ++z) r8[z] = fmaf(o[z], gg, x8[z]);
    *(float4*)&out[(size_t)i * D + q * 8] = *(float4*)&r8[0];
    *(float4*)&out[(size_t)i * D + q * 8 + 4] = *(float4*)&r8[4];
  }
}

extern "C" void kernel_launch(void* const* d_in, const int* in_sizes, int n_in,
                              void* d_out, int out_size, void* d_ws, size_t ws_size,
                              hipStream_t stream) {
  const float* x = (const float*)d_in[0];
  const int* ei = (const int*)d_in[1];
  const float* gamma = (const float*)d_in[2];
  const float* beta = (const float*)d_in[3];
  const float* Wl = (const float*)d_in[4];
  const float* bL = (const float*)d_in[5];
  const float* Wr = (const float*)d_in[6];
  const float* bR = (const float*)d_in[7];
  const float* att = (const float*)d_in[8];
  const float* bias = (const float*)d_in[9];
  const float* scale = (const float*)d_in[10];
  float* out = (float*)d_out;

  // workspace layout (~49 MB)
  int2* bucketed = (int2*)d_ws;        // E2 pairs
  int* csr = (int*)(bucketed + E2);    // E2
  int* rowptr = csr + E2;              // N+1
  int* bcnt = rowptr + N_NODES + 1;    // 64
  int* boff = bcnt + 64;               // NBUCK+1 (pad 64)
  int* bcur = boff + 64;               // 64
  float* hnorm = (float*)(bcur + 64);  // N
  __hip_bfloat16* hb = (__hip_bfloat16*)(hnorm + N_NODES);
  __hip_bfloat16* Wt = hb + (size_t)N_NODES * D;  // 256*128
  _Float16* xlh = (_Float16*)(Wt + 256 * D);
  _Float16* xrh = xlh + (size_t)N_NODES * D;

  hipMemsetAsync(bcnt, 0, 64 * sizeof(int), stream);
  k_pre<<<NB_LN + NB_W + NB_SC, 256, 0, stream>>>(x, gamma, beta, Wl, Wr, ei, hb,
                                                  hnorm, Wt, bcnt);
  k_bscan<<<1, 64, 0, stream>>>(bcnt, boff, bcur, rowptr);
  k_bscatter<<<NB_SC, 256, 0, stream>>>(ei, bcur, bucketed);
  k_csr<<<NBUCK, 256, 0, stream>>>(bucketed, boff, rowptr, csr);
  k_gemm2<<<dim3((N_NODES + 127) / 128, 2), 256, 0, stream>>>(hb, Wt, bL, bR, xlh, xrh);
  k_node<<<(N_NODES + 3) / 4, 256, 0, stream>>>(x, xlh, xrh, hnorm, rowptr, csr, att,
                                                bias, scale, out);
}

// Round 8
// 150.142 us; speedup vs baseline: 1.1735x; 1.0883x over previous
//
#include <hip/hip_runtime.h>
#include <hip/hip_bf16.h>
#include <math.h>

#define N_NODES 50000
#define N_EDGES 800000
#define E2 (N_EDGES + N_NODES)
#define D 128

#define NB_LN 12500
#define NB_W 128

#define BSHIFT 10
#define NBUCK 49  // ceil(50000 / 1024)
#define SCHUNK 4096
#define NB_SC ((E2 + SCHUNK - 1) / SCHUNK)

typedef short short8 __attribute__((ext_vector_type(8)));
typedef float f32x4 __attribute__((ext_vector_type(4)));
typedef _Float16 h16x2 __attribute__((ext_vector_type(2)));
typedef _Float16 h16x8 __attribute__((ext_vector_type(8)));

__device__ __forceinline__ float waveReduceSum(float v) {
#pragma unroll
  for (int off = 32; off >= 1; off >>= 1) v += __shfl_xor(v, off);
  return v;
}

__device__ __forceinline__ h16x2 shfl_xor_h2(h16x2 v, int off) {
  int r = __shfl_xor(__builtin_bit_cast(int, v), off);
  return __builtin_bit_cast(h16x2, r);
}

// Fused: LayerNorm->ReLU->hb + hnorm | W transpose+cvt | bucket count.
__global__ void __launch_bounds__(256) k_pre(
    const float* __restrict__ x, const float* __restrict__ gamma,
    const float* __restrict__ beta, const float* __restrict__ Wl,
    const float* __restrict__ Wr, const int* __restrict__ ei,
    __hip_bfloat16* __restrict__ hb, float* __restrict__ hnorm,
    __hip_bfloat16* __restrict__ Wt, int* __restrict__ bcnt) {
  const int b = blockIdx.x;
  if (b < NB_LN) {
    int wid = threadIdx.x >> 6;
    int lane = threadIdx.x & 63;
    int i = b * 4 + wid;
    const float2 xv = *(const float2*)&x[(size_t)i * D + lane * 2];
    float s = waveReduceSum(xv.x + xv.y);
    float mean = s * (1.0f / D);
    float d0 = xv.x - mean, d1 = xv.y - mean;
    float vs = waveReduceSum(d0 * d0 + d1 * d1);
    float rstd = rsqrtf(vs * (1.0f / D) + 1e-5f);
    const float2 g = *(const float2*)&gamma[lane * 2];
    const float2 bb = *(const float2*)&beta[lane * 2];
    float h0 = fmaxf(d0 * rstd * g.x + bb.x, 0.0f);
    float h1 = fmaxf(d1 * rstd * g.y + bb.y, 0.0f);
    __hip_bfloat162 hv;
    hv.x = __float2bfloat16(h0);
    hv.y = __float2bfloat16(h1);
    *(__hip_bfloat162*)&hb[(size_t)i * D + lane * 2] = hv;
    float ns = waveReduceSum(h0 * h0 + h1 * h1);
    if (lane == 0) hnorm[i] = sqrtf(ns);
  } else if (b < NB_LN + NB_W) {
    int local = b - NB_LN;
    int n = local * 2 + (threadIdx.x >> 7);
    int k = threadIdx.x & 127;
    float v = (n < D) ? Wl[(size_t)k * D + n] : Wr[(size_t)k * D + (n - D)];
    Wt[n * D + k] = __float2bfloat16(v);
  } else {
    __shared__ int c[64];
    const int t = threadIdx.x;
    if (t < 64) c[t] = 0;
    __syncthreads();
    const int s0 = (b - NB_LN - NB_W) * SCHUNK;
#pragma unroll
    for (int k = 0; k < 16; ++k) {
      int e = s0 + t + k * 256;
      if (e < E2) {
        int dst = (e < N_EDGES) ? ei[N_EDGES + e] : (e - N_EDGES);
        atomicAdd(&c[dst >> BSHIFT], 1);
      }
    }
    __syncthreads();
    if (t < 64 && c[t]) atomicAdd(&bcnt[t], c[t]);
  }
}

// bf16 MFMA GEMM: 128x128 tile, K=128 in LDS, 4 waves each 64x64.
// Output stored as f16 (feeds packed-f16 k_node math).
__global__ void __launch_bounds__(256) k_gemm2(
    const __hip_bfloat16* __restrict__ hb, const __hip_bfloat16* __restrict__ Wt,
    const float* __restrict__ bL, const float* __restrict__ bR,
    _Float16* __restrict__ xlh, _Float16* __restrict__ xrh) {
  __shared__ unsigned short As[128 * 128];
  __shared__ unsigned short Bs[128 * 128];
  const int t = threadIdx.x;
  const int row0 = blockIdx.x * 128;
  const int nhalf = blockIdx.y;
  const unsigned short* hu = (const unsigned short*)hb;
  const unsigned short* wu = (const unsigned short*)Wt;
#pragma unroll
  for (int it = 0; it < 8; ++it) {
    int idx = t + it * 256;
    int r = idx >> 4, g = idx & 15;
    int gs = g ^ (r & 15);
    short8 av = {};
    int grow = row0 + r;
    if (grow < N_NODES) av = *(const short8*)&hu[(size_t)grow * D + g * 8];
    *(short8*)&As[r * 128 + gs * 8] = av;
    short8 bv = *(const short8*)&wu[(size_t)(nhalf * 128 + r) * D + g * 8];
    *(short8*)&Bs[r * 128 + gs * 8] = bv;
  }
  __syncthreads();
  const int w = t >> 6, lane = t & 63;
  const int wm = (w >> 1) * 64, wn = (w & 1) * 64;
  const int lr = lane & 15, lq = lane >> 4;
  f32x4 acc[4][4] = {};
#pragma unroll
  for (int kb = 0; kb < 4; ++kb) {
    short8 af[4], bfr[4];
#pragma unroll
    for (int mi = 0; mi < 4; ++mi) {
      int r = wm + mi * 16 + lr;
      int g = (kb * 4 + lq) ^ (r & 15);
      af[mi] = *(const short8*)&As[r * 128 + g * 8];
    }
#pragma unroll
    for (int ni = 0; ni < 4; ++ni) {
      int r = wn + ni * 16 + lr;
      int g = (kb * 4 + lq) ^ (r & 15);
      bfr[ni] = *(const short8*)&Bs[r * 128 + g * 8];
    }
#pragma unroll
    for (int mi = 0; mi < 4; ++mi)
#pragma unroll
      for (int ni = 0; ni < 4; ++ni)
        acc[mi][ni] =
            __builtin_amdgcn_mfma_f32_16x16x32_bf16(af[mi], bfr[ni], acc[mi][ni], 0, 0, 0);
  }
  const float* bb = (nhalf == 0) ? bL : bR;
  _Float16* dst = (nhalf == 0) ? xlh : xrh;
#pragma unroll
  for (int mi = 0; mi < 4; ++mi) {
#pragma unroll
    for (int ni = 0; ni < 4; ++ni) {
#pragma unroll
      for (int r = 0; r < 4; ++r) {
        int row = row0 + wm + mi * 16 + lq * 4 + r;
        int col = wn + ni * 16 + lr;
        if (row < N_NODES)
          dst[(size_t)row * D + col] = (_Float16)(acc[mi][ni][r] + bb[col]);
      }
    }
  }
}

// Scatter (src,dst) pairs into bucket-grouped array. Per-block two-phase;
// bucket base offsets computed in-block from bcnt (wave-0 exclusive scan),
// disjoint ranges reserved via zero-initialized global cursors cnt0.
__global__ void __launch_bounds__(256) k_bscatter(const int* __restrict__ ei,
                                                  const int* __restrict__ bcnt,
                                                  int* __restrict__ cnt0,
                                                  int2* __restrict__ bucketed) {
  __shared__ int c[64], base[64], boffL[64];
  const int t = threadIdx.x;
  if (t < 64) {  // wave 0: exclusive scan of bucket counts
    int v = (t < NBUCK) ? bcnt[t] : 0;
    int incl = v;
#pragma unroll
    for (int off = 1; off < 64; off <<= 1) {
      int u = __shfl_up(incl, off);
      if (t >= off) incl += u;
    }
    boffL[t] = incl - v;
    c[t] = 0;
  }
  __syncthreads();
  const int s0 = blockIdx.x * SCHUNK;
#pragma unroll
  for (int k = 0; k < 16; ++k) {
    int e = s0 + t + k * 256;
    if (e < E2) {
      int dst = (e < N_EDGES) ? ei[N_EDGES + e] : (e - N_EDGES);
      atomicAdd(&c[dst >> BSHIFT], 1);
    }
  }
  __syncthreads();
  if (t < 64) {
    base[t] = c[t] ? (boffL[t] + atomicAdd(&cnt0[t], c[t])) : 0;
    c[t] = 0;
  }
  __syncthreads();
#pragma unroll
  for (int k = 0; k < 16; ++k) {
    int e = s0 + t + k * 256;
    if (e < E2) {
      int src, dst;
      if (e < N_EDGES) {
        src = ei[e];
        dst = ei[N_EDGES + e];
      } else {
        src = dst = e - N_EDGES;
      }
      int b = dst >> BSHIFT;
      int pos = base[b] + atomicAdd(&c[b], 1);
      bucketed[pos] = make_int2(src, dst);
    }
  }
}

// One block per bucket: degree count + scan in LDS -> rowptr, then scatter
// csr within the bucket's contiguous (L2-local) window. Own segment bounds
// computed from bcnt via masked wave-reduce.
__global__ void __launch_bounds__(256) k_csr(const int2* __restrict__ bucketed,
                                             const int* __restrict__ bcnt,
                                             int* __restrict__ rowptr,
                                             int* __restrict__ csr) {
  __shared__ int cnt[1024], tsum[256], cursor[1024];
  __shared__ int se0, se1;
  const int b = blockIdx.x;
  const int base = b << BSHIFT;
  const int nnode = min(1024, N_NODES - base);
  const int t = threadIdx.x;
  if (t < 64) {
    int v = (t < b) ? bcnt[t] : 0;
#pragma unroll
    for (int off = 32; off >= 1; off >>= 1) v += __shfl_xor(v, off);
    if (t == 0) {
      se0 = v;
      se1 = v + bcnt[b];
    }
  }
  if (b == 0 && t == 0) rowptr[N_NODES] = E2;
  for (int n = t; n < 1024; n += 256) cnt[n] = 0;
  __syncthreads();
  const int e0 = se0, e1 = se1;
  for (int e = e0 + t; e < e1; e += 256) {
    int2 pr = bucketed[e];
    atomicAdd(&cnt[pr.y - base], 1);
  }
  __syncthreads();
  const int n0 = t * 4;
  const int c0 = cnt[n0], c1 = cnt[n0 + 1], c2 = cnt[n0 + 2], c3 = cnt[n0 + 3];
  const int s = c0 + c1 + c2 + c3;
  tsum[t] = s;
  __syncthreads();
  for (int off = 1; off < 256; off <<= 1) {
    int u = 0;
    if (t >= off) u = tsum[t - off];
    __syncthreads();
    if (t >= off) tsum[t] += u;
    __syncthreads();
  }
  const int ebase = e0 + tsum[t] - s;  // exclusive prefix
  const int r0 = ebase, r1 = r0 + c0, r2 = r1 + c1, r3 = r2 + c2;
  cursor[n0] = r0;
  cursor[n0 + 1] = r1;
  cursor[n0 + 2] = r2;
  cursor[n0 + 3] = r3;
  if (n0 < nnode) rowptr[base + n0] = r0;
  if (n0 + 1 < nnode) rowptr[base + n0 + 1] = r1;
  if (n0 + 2 < nnode) rowptr[base + n0 + 2] = r2;
  if (n0 + 3 < nnode) rowptr[base + n0 + 3] = r3;
  __syncthreads();
  for (int e = e0 + t; e < e1; e += 256) {
    int2 pr = bucketed[e];
    int pos = atomicAdd(&cursor[pr.y - base], 1);
    csr[pos] = pr.x;
  }
}

// Fused GATv2 edge phase. One wave per node; 4 edges per iteration
// (16 lanes/edge, 8 dims/lane), gathers prefetched 2 iterations deep.
// Packed f16 score math (v_pk_add/mul/max_f16 + v_dot2_f32_f16) and packed
// f16 aggregation (v_pk_fma_f16); S in f32. Direct exp (scores O(+-3),
// softmax shift-invariant, fp32-safe).
__global__ void __launch_bounds__(256) k_node(
    const float* __restrict__ x, const _Float16* __restrict__ xlh,
    const _Float16* __restrict__ xrh, const float* __restrict__ hnorm,
    const int* __restrict__ rowptr, const int* __restrict__ csr,
    const float* __restrict__ att, const float* __restrict__ bias,
    const float* __restrict__ scale, float* __restrict__ out) {
  const int wid = threadIdx.x >> 6;
  const int lane = threadIdx.x & 63;
  const int i = blockIdx.x * 4 + wid;
  if (i >= N_NODES) return;
  const int g = lane >> 4;  // edge subgroup 0..3
  const int q = lane & 15;  // dim quad: dims q*8 .. q*8+7 ; head = q>>2

  const h16x8 xrv = *(const h16x8*)(xrh + (size_t)i * D + q * 8);
  h16x2 xr2[4], at2[4];
  {
    const float4 a0 = *(const float4*)&att[q * 8];
    const float4 a1 = *(const float4*)&att[q * 8 + 4];
    at2[0] = (h16x2){(_Float16)a0.x, (_Float16)a0.y};
    at2[1] = (h16x2){(_Float16)a0.z, (_Float16)a0.w};
    at2[2] = (h16x2){(_Float16)a1.x, (_Float16)a1.y};
    at2[3] = (h16x2){(_Float16)a1.z, (_Float16)a1.w};
#pragma unroll
    for (int z = 0; z < 4; ++z) xr2[z] = (h16x2){xrv[2 * z], xrv[2 * z + 1]};
  }
  const h16x2 c02 = {(_Float16)0.2f, (_Float16)0.2f};

  const int e0 = rowptr[i], e1 = rowptr[i + 1];
  h16x2 A2[4] = {};
  float S = 0.f;

  // 2-deep software pipeline: two row-gathers in flight per lane
  int j0 = csr[min(e0 + g, e1 - 1)];
  h16x8 r0 = *(const h16x8*)(xlh + (size_t)j0 * D + q * 8);
  int j1 = csr[min(e0 + 4 + g, e1 - 1)];
  h16x8 r1 = *(const h16x8*)(xlh + (size_t)j1 * D + q * 8);
  int j2 = csr[min(e0 + 8 + g, e1 - 1)];

  for (int e = e0; e < e1; e += 4) {
    const h16x8 cur = r0;
    r0 = r1;
    r1 = *(const h16x8*)(xlh + (size_t)j2 * D + q * 8);
    j2 = csr[min(e + 12 + g, e1 - 1)];
    const bool ok = (e + g) < e1;

    h16x2 v2[4];
    v2[0] = (h16x2){cur[0], cur[1]};
    v2[1] = (h16x2){cur[2], cur[3]};
    v2[2] = (h16x2){cur[4], cur[5]};
    v2[3] = (h16x2){cur[6], cur[7]};
    float sc = 0.f;
#pragma unroll
    for (int z = 0; z < 4; ++z) {
      h16x2 f = v2[z] + xr2[z];
      h16x2 lf = __builtin_elementwise_max(f, f * c02);
      sc = __builtin_amdgcn_fdot2(lf, at2[z], sc, false);
    }
    sc += __shfl_xor(sc, 1);
    sc += __shfl_xor(sc, 2);
    const float p = ok ? __expf(sc) : 0.f;
    S += p;
    const _Float16 ph = (_Float16)p;
    const h16x2 p2 = {ph, ph};
#pragma unroll
    for (int z = 0; z < 4; ++z) A2[z] = v2[z] * p2 + A2[z];
  }

  // combine the 4 edge subgroups (lanes l, l+16, l+32, l+48 share dims)
#pragma unroll
  for (int off = 16; off <= 32; off <<= 1) {
#pragma unroll
    for (int z = 0; z < 4; ++z) A2[z] = A2[z] + shfl_xor_h2(A2[z], off);
    S += __shfl_xor(S, off);
  }

  const float si = 1.0f / S;
  float o[8];
  float b8[8];
  *(float4*)&b8[0] = *(const float4*)&bias[q * 8];
  *(float4*)&b8[4] = *(const float4*)&bias[q * 8 + 4];
  float dot = 0.f;
#pragma unroll
  for (int z = 0; z < 4; ++z) {
    o[2 * z] = fmaf((float)A2[z][0], si, b8[2 * z]);
    o[2 * z + 1] = fmaf((float)A2[z][1], si, b8[2 * z + 1]);
    dot = fmaf(o[2 * z], o[2 * z], dot);
    dot = fmaf(o[2 * z + 1], o[2 * z + 1], dot);
  }
  const float nrm = sqrtf(waveReduceSum(dot) * 0.25f);  // dims replicated 4x
  const float gg = hnorm[i] * scale[0] / fmaxf(nrm, 1e-12f);

  if (lane < 16) {
    float x8[8];
    *(float4*)&x8[0] = *(const float4*)&x[(size_t)i * D + q * 8];
    *(float4*)&x8[4] = *(const float4*)&x[(size_t)i * D + q * 8 + 4];
    float r8[8];
#pragma unroll
    for (int z = 0; z < 8; ++z) r8[z] = fmaf(o[z], gg, x8[z]);
    *(float4*)&out[(size_t)i * D + q * 8] = *(float4*)&r8[0];
    *(float4*)&out[(size_t)i * D + q * 8 + 4] = *(float4*)&r8[4];
  }
}

extern "C" void kernel_launch(void* const* d_in, const int* in_sizes, int n_in,
                              void* d_out, int out_size, void* d_ws, size_t ws_size,
                              hipStream_t stream) {
  const float* x = (const float*)d_in[0];
  const int* ei = (const int*)d_in[1];
  const float* gamma = (const float*)d_in[2];
  const float* beta = (const float*)d_in[3];
  const float* Wl = (const float*)d_in[4];
  const float* bL = (const float*)d_in[5];
  const float* Wr = (const float*)d_in[6];
  const float* bR = (const float*)d_in[7];
  const float* att = (const float*)d_in[8];
  const float* bias = (const float*)d_in[9];
  const float* scale = (const float*)d_in[10];
  float* out = (float*)d_out;

  // workspace layout (~49 MB, 16B-aligned segments)
  int2* bucketed = (int2*)d_ws;          // E2 pairs
  int* csr = (int*)(bucketed + E2);      // E2
  int* rowptr = csr + E2;                // N+1 (padded to N+16)
  int* bcnt = rowptr + N_NODES + 16;     // 64
  int* cnt0 = bcnt + 64;                 // 64
  float* hnorm = (float*)(cnt0 + 64);    // N
  __hip_bfloat16* hb = (__hip_bfloat16*)(hnorm + N_NODES);
  __hip_bfloat16* Wt = hb + (size_t)N_NODES * D;  // 256*128
  _Float16* xlh = (_Float16*)(Wt + 256 * D);
  _Float16* xrh = xlh + (size_t)N_NODES * D;

  hipMemsetAsync(bcnt, 0, 128 * sizeof(int), stream);
  k_pre<<<NB_LN + NB_W + NB_SC, 256, 0, stream>>>(x, gamma, beta, Wl, Wr, ei, hb,
                                                  hnorm, Wt, bcnt);
  k_bscatter<<<NB_SC, 256, 0, stream>>>(ei, bcnt, cnt0, bucketed);
  k_csr<<<NBUCK, 256, 0, stream>>>(bucketed, bcnt, rowptr, csr);
  k_gemm2<<<dim3((N_NODES + 127) / 128, 2), 256, 0, stream>>>(hb, Wt, bL, bR, xlh, xrh);
  k_node<<<(N_NODES + 3) / 4, 256, 0, stream>>>(x, xlh, xrh, hnorm, rowptr, csr, att,
                                                bias, scale, out);
}

// Round 9
// 116.662 us; speedup vs baseline: 1.5102x; 1.2870x over previous
//
#include <hip/hip_runtime.h>
#include <hip/hip_bf16.h>
#include <math.h>

#define N_NODES 50000
#define N_EDGES 800000
#define E2 (N_EDGES + N_NODES)
#define D 128

#define NB_LN 12500
#define NB_W 128

#define BSHIFT 8
#define NBUCK 196  // ceil(50000 / 256)
#define SCHUNK 4096
#define NB_SC ((E2 + SCHUNK - 1) / SCHUNK)
#define NB_GEMM (((N_NODES + 127) / 128) * 2)  // 782

typedef short short8 __attribute__((ext_vector_type(8)));
typedef float f32x4 __attribute__((ext_vector_type(4)));
typedef _Float16 h16x2 __attribute__((ext_vector_type(2)));
typedef _Float16 h16x8 __attribute__((ext_vector_type(8)));

__device__ __forceinline__ float waveReduceSum(float v) {
#pragma unroll
  for (int off = 32; off >= 1; off >>= 1) v += __shfl_xor(v, off);
  return v;
}

__device__ __forceinline__ h16x2 shfl_xor_h2(h16x2 v, int off) {
  int r = __shfl_xor(__builtin_bit_cast(int, v), off);
  return __builtin_bit_cast(h16x2, r);
}

// Fused: LayerNorm->ReLU->hb + hnorm | W transpose+cvt | bucket count.
__global__ void __launch_bounds__(256) k_pre(
    const float* __restrict__ x, const float* __restrict__ gamma,
    const float* __restrict__ beta, const float* __restrict__ Wl,
    const float* __restrict__ Wr, const int* __restrict__ ei,
    __hip_bfloat16* __restrict__ hb, float* __restrict__ hnorm,
    __hip_bfloat16* __restrict__ Wt, int* __restrict__ bcnt) {
  const int b = blockIdx.x;
  if (b < NB_LN) {
    int wid = threadIdx.x >> 6;
    int lane = threadIdx.x & 63;
    int i = b * 4 + wid;
    const float2 xv = *(const float2*)&x[(size_t)i * D + lane * 2];
    float s = waveReduceSum(xv.x + xv.y);
    float mean = s * (1.0f / D);
    float d0 = xv.x - mean, d1 = xv.y - mean;
    float vs = waveReduceSum(d0 * d0 + d1 * d1);
    float rstd = rsqrtf(vs * (1.0f / D) + 1e-5f);
    const float2 g = *(const float2*)&gamma[lane * 2];
    const float2 bb = *(const float2*)&beta[lane * 2];
    float h0 = fmaxf(d0 * rstd * g.x + bb.x, 0.0f);
    float h1 = fmaxf(d1 * rstd * g.y + bb.y, 0.0f);
    __hip_bfloat162 hv;
    hv.x = __float2bfloat16(h0);
    hv.y = __float2bfloat16(h1);
    *(__hip_bfloat162*)&hb[(size_t)i * D + lane * 2] = hv;
    float ns = waveReduceSum(h0 * h0 + h1 * h1);
    if (lane == 0) hnorm[i] = sqrtf(ns);
  } else if (b < NB_LN + NB_W) {
    int local = b - NB_LN;
    int n = local * 2 + (threadIdx.x >> 7);
    int k = threadIdx.x & 127;
    float v = (n < D) ? Wl[(size_t)k * D + n] : Wr[(size_t)k * D + (n - D)];
    Wt[n * D + k] = __float2bfloat16(v);
  } else {
    __shared__ int c[256];
    const int t = threadIdx.x;
    c[t] = 0;
    __syncthreads();
    const int s0 = (b - NB_LN - NB_W) * SCHUNK;
#pragma unroll
    for (int k = 0; k < 16; ++k) {
      int e = s0 + t + k * 256;
      if (e < E2) {
        int dst = (e < N_EDGES) ? ei[N_EDGES + e] : (e - N_EDGES);
        atomicAdd(&c[dst >> BSHIFT], 1);
      }
    }
    __syncthreads();
    if (c[t]) atomicAdd(&bcnt[t], c[t]);
  }
}

// Scatter (src,dst) pairs into bucket-grouped array. Per-block two-phase;
// bucket base offsets computed in-block from bcnt (LDS exclusive scan),
// disjoint ranges reserved via zero-initialized global cursors cnt0.
__global__ void __launch_bounds__(256) k_bscatter(const int* __restrict__ ei,
                                                  const int* __restrict__ bcnt,
                                                  int* __restrict__ cnt0,
                                                  int2* __restrict__ bucketed) {
  __shared__ int c[256], base[256], sd[256];
  const int t = threadIdx.x;
  const int own = (t < NBUCK) ? bcnt[t] : 0;
  sd[t] = own;
  c[t] = 0;
  __syncthreads();
  for (int off = 1; off < 256; off <<= 1) {
    int u = 0;
    if (t >= off) u = sd[t - off];
    __syncthreads();
    if (t >= off) sd[t] += u;
    __syncthreads();
  }
  const int boffL = sd[t] - own;  // exclusive prefix
  const int s0 = blockIdx.x * SCHUNK;
#pragma unroll
  for (int k = 0; k < 16; ++k) {
    int e = s0 + t + k * 256;
    if (e < E2) {
      int dst = (e < N_EDGES) ? ei[N_EDGES + e] : (e - N_EDGES);
      atomicAdd(&c[dst >> BSHIFT], 1);
    }
  }
  __syncthreads();
  if (t < NBUCK) {
    base[t] = c[t] ? (boffL + atomicAdd(&cnt0[t], c[t])) : 0;
    c[t] = 0;
  }
  __syncthreads();
#pragma unroll
  for (int k = 0; k < 16; ++k) {
    int e = s0 + t + k * 256;
    if (e < E2) {
      int src, dst;
      if (e < N_EDGES) {
        src = ei[e];
        dst = ei[N_EDGES + e];
      } else {
        src = dst = e - N_EDGES;
      }
      int bk = dst >> BSHIFT;
      int pos = base[bk] + atomicAdd(&c[bk], 1);
      bucketed[pos] = make_int2(src, dst);
    }
  }
}

// Fused middle kernel: blocks [0,NBUCK) build CSR (one block per 256-node
// bucket); blocks [NBUCK, NBUCK+NB_GEMM) run the bf16 MFMA GEMM.
// One static 64KB LDS block, reinterpreted per role.
__global__ void __launch_bounds__(256) k_mid(
    const int2* __restrict__ bucketed, const int* __restrict__ bcnt,
    int* __restrict__ rowptr, int* __restrict__ csr,
    const __hip_bfloat16* __restrict__ hb, const __hip_bfloat16* __restrict__ Wt,
    const float* __restrict__ bL, const float* __restrict__ bR,
    _Float16* __restrict__ xlh, _Float16* __restrict__ xrh) {
  __shared__ char smem[65536];
  const int t = threadIdx.x;
  if (blockIdx.x < NBUCK) {
    // ---- CSR build for bucket b ----
    int* cnt = (int*)smem;          // 256
    int* tsum = cnt + 256;          // 256
    int* cursor = tsum + 256;       // 256
    int* red = cursor + 256;        // 256
    const int b = blockIdx.x;
    const int base = b << BSHIFT;
    const int nnode = min(256, N_NODES - base);
    // segment bounds: e0 = sum bcnt[0..b)
    red[t] = (t < b) ? bcnt[t] : 0;
    cnt[t] = 0;
    __syncthreads();
    for (int off = 128; off >= 1; off >>= 1) {
      if (t < off) red[t] += red[t + off];
      __syncthreads();
    }
    const int e0 = red[0], e1 = red[0] + bcnt[b];
    if (b == 0 && t == 0) rowptr[N_NODES] = E2;
    for (int e = e0 + t; e < e1; e += 256) {
      int2 pr = bucketed[e];
      atomicAdd(&cnt[pr.y - base], 1);
    }
    __syncthreads();
    const int own = cnt[t];
    tsum[t] = own;
    __syncthreads();
    for (int off = 1; off < 256; off <<= 1) {
      int u = 0;
      if (t >= off) u = tsum[t - off];
      __syncthreads();
      if (t >= off) tsum[t] += u;
      __syncthreads();
    }
    const int ebase = e0 + tsum[t] - own;  // exclusive prefix
    cursor[t] = ebase;
    if (t < nnode) rowptr[base + t] = ebase;
    __syncthreads();
    for (int e = e0 + t; e < e1; e += 256) {
      int2 pr = bucketed[e];
      int pos = atomicAdd(&cursor[pr.y - base], 1);
      csr[pos] = pr.x;
    }
  } else {
    // ---- GEMM tile ----
    unsigned short* As = (unsigned short*)smem;  // 128*128
    unsigned short* Bs = As + 128 * 128;
    const int bid = blockIdx.x - NBUCK;
    const int row0 = (bid >> 1) * 128;
    const int nhalf = bid & 1;
    const unsigned short* hu = (const unsigned short*)hb;
    const unsigned short* wu = (const unsigned short*)Wt;
#pragma unroll
    for (int it = 0; it < 8; ++it) {
      int idx = t + it * 256;
      int r = idx >> 4, g = idx & 15;
      int gs = g ^ (r & 15);
      short8 av = {};
      int grow = row0 + r;
      if (grow < N_NODES) av = *(const short8*)&hu[(size_t)grow * D + g * 8];
      *(short8*)&As[r * 128 + gs * 8] = av;
      short8 bv = *(const short8*)&wu[(size_t)(nhalf * 128 + r) * D + g * 8];
      *(short8*)&Bs[r * 128 + gs * 8] = bv;
    }
    __syncthreads();
    const int w = t >> 6, lane = t & 63;
    const int wm = (w >> 1) * 64, wn = (w & 1) * 64;
    const int lr = lane & 15, lq = lane >> 4;
    f32x4 acc[4][4] = {};
#pragma unroll
    for (int kb = 0; kb < 4; ++kb) {
      short8 af[4], bfr[4];
#pragma unroll
      for (int mi = 0; mi < 4; ++mi) {
        int r = wm + mi * 16 + lr;
        int g = (kb * 4 + lq) ^ (r & 15);
        af[mi] = *(const short8*)&As[r * 128 + g * 8];
      }
#pragma unroll
      for (int ni = 0; ni < 4; ++ni) {
        int r = wn + ni * 16 + lr;
        int g = (kb * 4 + lq) ^ (r & 15);
        bfr[ni] = *(const short8*)&Bs[r * 128 + g * 8];
      }
#pragma unroll
      for (int mi = 0; mi < 4; ++mi)
#pragma unroll
        for (int ni = 0; ni < 4; ++ni)
          acc[mi][ni] = __builtin_amdgcn_mfma_f32_16x16x32_bf16(af[mi], bfr[ni],
                                                                acc[mi][ni], 0, 0, 0);
    }
    const float* bb = (nhalf == 0) ? bL : bR;
    _Float16* dst = (nhalf == 0) ? xlh : xrh;
#pragma unroll
    for (int mi = 0; mi < 4; ++mi) {
#pragma unroll
      for (int ni = 0; ni < 4; ++ni) {
#pragma unroll
        for (int r = 0; r < 4; ++r) {
          int row = row0 + wm + mi * 16 + lq * 4 + r;
          int col = wn + ni * 16 + lr;
          if (row < N_NODES)
            dst[(size_t)row * D + col] = (_Float16)(acc[mi][ni][r] + bb[col]);
        }
      }
    }
  }
}

// Fused GATv2 edge phase. One wave per node; 4 edges per iteration
// (16 lanes/edge, 8 dims/lane), gathers prefetched 3 iterations deep.
// Packed f16 score math (v_pk_add/mul/max_f16 + v_dot2_f32_f16) and packed
// f16 aggregation; S in f32. Direct exp (scores O(+-3), shift-invariant).
__global__ void __launch_bounds__(256) k_node(
    const float* __restrict__ x, const _Float16* __restrict__ xlh,
    const _Float16* __restrict__ xrh, const float* __restrict__ hnorm,
    const int* __restrict__ rowptr, const int* __restrict__ csr,
    const float* __restrict__ att, const float* __restrict__ bias,
    const float* __restrict__ scale, float* __restrict__ out) {
  const int wid = threadIdx.x >> 6;
  const int lane = threadIdx.x & 63;
  const int i = blockIdx.x * 4 + wid;
  if (i >= N_NODES) return;
  const int g = lane >> 4;  // edge subgroup 0..3
  const int q = lane & 15;  // dim quad: dims q*8 .. q*8+7 ; head = q>>2

  const h16x8 xrv = *(const h16x8*)(xrh + (size_t)i * D + q * 8);
  h16x2 xr2[4], at2[4];
  {
    const float4 a0 = *(const float4*)&att[q * 8];
    const float4 a1 = *(const float4*)&att[q * 8 + 4];
    at2[0] = (h16x2){(_Float16)a0.x, (_Float16)a0.y};
    at2[1] = (h16x2){(_Float16)a0.z, (_Float16)a0.w};
    at2[2] = (h16x2){(_Float16)a1.x, (_Float16)a1.y};
    at2[3] = (h16x2){(_Float16)a1.z, (_Float16)a1.w};
#pragma unroll
    for (int z = 0; z < 4; ++z) xr2[z] = (h16x2){xrv[2 * z], xrv[2 * z + 1]};
  }
  const h16x2 c02 = {(_Float16)0.2f, (_Float16)0.2f};

  const int e0 = rowptr[i], e1 = rowptr[i + 1];
  h16x2 A2[4] = {};
  float S = 0.f;

  // 3-deep software pipeline: three row-gathers in flight per lane
  int ja = csr[min(e0 + g, e1 - 1)];
  h16x8 r0 = *(const h16x8*)(xlh + (size_t)ja * D + q * 8);
  int jb = csr[min(e0 + 4 + g, e1 - 1)];
  h16x8 r1 = *(const h16x8*)(xlh + (size_t)jb * D + q * 8);
  int jc = csr[min(e0 + 8 + g, e1 - 1)];
  h16x8 r2 = *(const h16x8*)(xlh + (size_t)jc * D + q * 8);
  int jd = csr[min(e0 + 12 + g, e1 - 1)];

  for (int e = e0; e < e1; e += 4) {
    const h16x8 cur = r0;
    r0 = r1;
    r1 = r2;
    r2 = *(const h16x8*)(xlh + (size_t)jd * D + q * 8);
    jd = csr[min(e + 16 + g, e1 - 1)];
    const bool ok = (e + g) < e1;

    h16x2 v2[4];
    v2[0] = (h16x2){cur[0], cur[1]};
    v2[1] = (h16x2){cur[2], cur[3]};
    v2[2] = (h16x2){cur[4], cur[5]};
    v2[3] = (h16x2){cur[6], cur[7]};
    float sc = 0.f;
#pragma unroll
    for (int z = 0; z < 4; ++z) {
      h16x2 f = v2[z] + xr2[z];
      h16x2 lf = __builtin_elementwise_max(f, f * c02);
      sc = __builtin_amdgcn_fdot2(lf, at2[z], sc, false);
    }
    sc += __shfl_xor(sc, 1);
    sc += __shfl_xor(sc, 2);
    const float p = ok ? __expf(sc) : 0.f;
    S += p;
    const _Float16 ph = (_Float16)p;
    const h16x2 p2 = {ph, ph};
#pragma unroll
    for (int z = 0; z < 4; ++z) A2[z] = v2[z] * p2 + A2[z];
  }

  // combine the 4 edge subgroups (lanes l, l+16, l+32, l+48 share dims)
#pragma unroll
  for (int off = 16; off <= 32; off <<= 1) {
#pragma unroll
    for (int z = 0; z < 4; ++z) A2[z] = A2[z] + shfl_xor_h2(A2[z], off);
    S += __shfl_xor(S, off);
  }

  const float si = 1.0f / S;
  float o[8];
  float b8[8];
  *(float4*)&b8[0] = *(const float4*)&bias[q * 8];
  *(float4*)&b8[4] = *(const float4*)&bias[q * 8 + 4];
  float dot = 0.f;
#pragma unroll
  for (int z = 0; z < 4; ++z) {
    o[2 * z] = fmaf((float)A2[z][0], si, b8[2 * z]);
    o[2 * z + 1] = fmaf((float)A2[z][1], si, b8[2 * z + 1]);
    dot = fmaf(o[2 * z], o[2 * z], dot);
    dot = fmaf(o[2 * z + 1], o[2 * z + 1], dot);
  }
  const float nrm = sqrtf(waveReduceSum(dot) * 0.25f);  // dims replicated 4x
  const float gg = hnorm[i] * scale[0] / fmaxf(nrm, 1e-12f);

  if (lane < 16) {
    float x8[8];
    *(float4*)&x8[0] = *(const float4*)&x[(size_t)i * D + q * 8];
    *(float4*)&x8[4] = *(const float4*)&x[(size_t)i * D + q * 8 + 4];
    float r8[8];
#pragma unroll
    for (int z = 0; z < 8; ++z) r8[z] = fmaf(o[z], gg, x8[z]);
    *(float4*)&out[(size_t)i * D + q * 8] = *(float4*)&r8[0];
    *(float4*)&out[(size_t)i * D + q * 8 + 4] = *(float4*)&r8[4];
  }
}

extern "C" void kernel_launch(void* const* d_in, const int* in_sizes, int n_in,
                              void* d_out, int out_size, void* d_ws, size_t ws_size,
                              hipStream_t stream) {
  const float* x = (const float*)d_in[0];
  const int* ei = (const int*)d_in[1];
  const float* gamma = (const float*)d_in[2];
  const float* beta = (const float*)d_in[3];
  const float* Wl = (const float*)d_in[4];
  const float* bL = (const float*)d_in[5];
  const float* Wr = (const float*)d_in[6];
  const float* bR = (const float*)d_in[7];
  const float* att = (const float*)d_in[8];
  const float* bias = (const float*)d_in[9];
  const float* scale = (const float*)d_in[10];
  float* out = (float*)d_out;

  // workspace layout (~49 MB, 16B-aligned segments)
  int2* bucketed = (int2*)d_ws;        // E2 pairs
  int* csr = (int*)(bucketed + E2);    // E2
  int* rowptr = csr + E2;              // N+1 (padded to N+16)
  int* bcnt = rowptr + N_NODES + 16;   // 256
  int* cnt0 = bcnt + 256;              // 256
  float* hnorm = (float*)(cnt0 + 256); // N
  __hip_bfloat16* hb = (__hip_bfloat16*)(hnorm + N_NODES);
  __hip_bfloat16* Wt = hb + (size_t)N_NODES * D;  // 256*128
  _Float16* xlh = (_Float16*)(Wt + 256 * D);
  _Float16* xrh = xlh + (size_t)N_NODES * D;

  hipMemsetAsync(bcnt, 0, 512 * sizeof(int), stream);
  k_pre<<<NB_LN + NB_W + NB_SC, 256, 0, stream>>>(x, gamma, beta, Wl, Wr, ei, hb,
                                                  hnorm, Wt, bcnt);
  k_bscatter<<<NB_SC, 256, 0, stream>>>(ei, bcnt, cnt0, bucketed);
  k_mid<<<NBUCK + NB_GEMM, 256, 0, stream>>>(bucketed, bcnt, rowptr, csr, hb, Wt,
                                             bL, bR, xlh, xrh);
  k_node<<<(N_NODES + 3) / 4, 256, 0, stream>>>(x, xlh, xrh, hnorm, rowptr, csr, att,
                                                bias, scale, out);
}